// Round 1
// baseline (716.260 us; speedup 1.0000x reference)
//
#include <hip/hip_runtime.h>
#include <math.h>

#define NNODES 50000
#define NEDGES 800000
#define HDIM 128
#define NINV 32
#define K1 288            // 2H + NINV
#define NTILES_E 25000    // NEDGES / 32
#define NTILES_N 1563     // ceil(NNODES / 32)

#define W1STRIDE 296      // ushorts per W1 LDS row (288+8): 148 dw == 20 mod 32 -> uniform banks, 16B aligned
#define U1STRIDE 264      // ushorts per Wu1 LDS row (256+8): 132 dw == 4 mod 32, 16B aligned
#define HSTRIDE 132       // h-buffer row stride in ushorts (128+4): 66 dw == 2 mod 32 -> u16 writes 2-way free
#define FSTRIDE 66        // same buffer viewed as f32: 66 dw/row (64 cols + 2 pad)

typedef float floatx4 __attribute__((ext_vector_type(4)));
typedef short short8  __attribute__((ext_vector_type(8)));

union V4S8 { uint4 u; short8 s; int2 d[2]; };

__device__ __forceinline__ float silu_f(float z) { return z / (1.0f + __expf(-z)); }

__device__ __forceinline__ unsigned short f2bf_rne(float f) {
    unsigned u = __float_as_uint(f);
    u += 0x7fffu + ((u >> 16) & 1u);
    return (unsigned short)(u >> 16);
}

// pack hi16(bf-truncate) of two floats into one dword: [lo | hi<<16]
__device__ __forceinline__ unsigned pk_bf(float hi, float lo) {
    return __builtin_amdgcn_perm(__float_as_uint(hi), __float_as_uint(lo), 0x07060302);
}

__device__ __forceinline__ short8 cvt8(float4 f0, float4 f1) {
    V4S8 v;
    v.u.x = pk_bf(f0.y, f0.x);
    v.u.y = pk_bf(f0.w, f0.z);
    v.u.z = pk_bf(f1.y, f1.x);
    v.u.w = pk_bf(f1.w, f1.z);
    return v.s;
}

__device__ __forceinline__ int adj_at(const void* adj, int is64, long long pos) {
    if (is64) return (int)((const long long*)adj)[pos];
    return ((const int*)adj)[pos];
}

__global__ __launch_bounds__(256) void detect_idx64(const int* __restrict__ adj32,
                                                    int* __restrict__ flag) {
    __shared__ int any_nz;
    if (threadIdx.x == 0) any_nz = 0;
    __syncthreads();
    int v = adj32[threadIdx.x * 2 + 1];
    if (v != 0) atomicOr(&any_nz, 1);
    __syncthreads();
    if (threadIdx.x == 0) *flag = (any_nz == 0) ? 1 : 0;
}

// Transpose + bf16(RNE) all four weight matrices: Wt[n][k] = bf16(W[k][n]).
__global__ __launch_bounds__(256) void prep_weights(
    const float* __restrict__ Wm1, const float* __restrict__ Wm2,
    const float* __restrict__ Wu1, const float* __restrict__ Wu2,
    unsigned short* __restrict__ Wm1t, unsigned short* __restrict__ Wm2t,
    unsigned short* __restrict__ Wu1t, unsigned short* __restrict__ Wu2t)
{
    int i = blockIdx.x * 256 + threadIdx.x;
    if (i < 128 * K1) {
        int n = i / K1, k = i % K1;
        Wm1t[i] = f2bf_rne(Wm1[k * HDIM + n]);
    } else if ((i -= 128 * K1) < 128 * HDIM) {
        int n = i / HDIM, k = i % HDIM;
        Wm2t[i] = f2bf_rne(Wm2[k * HDIM + n]);
    } else if ((i -= 128 * HDIM) < 128 * 256) {
        int n = i / 256, k = i % 256;
        Wu1t[i] = f2bf_rne(Wu1[k * HDIM + n]);
    } else if ((i -= 128 * 256) < 128 * HDIM) {
        int n = i / HDIM, k = i % HDIM;
        Wu2t[i] = f2bf_rne(Wu2[k * HDIM + n]);
    }
}

// ---------------- Counting sort of edges by destination node ----------------
__global__ __launch_bounds__(256) void hist_kernel(const void* __restrict__ adj,
                                                   const int* __restrict__ flagp,
                                                   int* __restrict__ hist)
{
    int e = blockIdx.x * 256 + threadIdx.x;
    if (e < NEDGES) {
        int r = adj_at(adj, *flagp, (long long)NEDGES + e);
        atomicAdd(&hist[r], 1);
    }
}

__global__ __launch_bounds__(1024) void scan_kernel(const int* __restrict__ hist,
                                                    int* __restrict__ cursor)
{
    __shared__ int sums[1024];
    const int t = threadIdx.x;
    const int CH = 49;                 // 1024*49 = 50176 >= NNODES
    int lo = t * CH; if (lo > NNODES) lo = NNODES;
    int hi = lo + CH; if (hi > NNODES) hi = NNODES;
    int s = 0;
    for (int i = lo; i < hi; ++i) s += hist[i];
    sums[t] = s;
    __syncthreads();
    for (int d = 1; d < 1024; d <<= 1) {
        int v = (t >= d) ? sums[t - d] : 0;
        __syncthreads();
        sums[t] += v;
        __syncthreads();
    }
    int base = (t == 0) ? 0 : sums[t - 1];
    for (int i = lo; i < hi; ++i) { cursor[i] = base; base += hist[i]; }
}

__global__ __launch_bounds__(256) void scatter_kernel(const void* __restrict__ adj,
                                                      const int* __restrict__ flagp,
                                                      int* __restrict__ cursor,
                                                      int* __restrict__ sSend,
                                                      int* __restrict__ sRec,
                                                      int* __restrict__ perm)
{
    int e = blockIdx.x * 256 + threadIdx.x;
    if (e < NEDGES) {
        int is64 = *flagp;
        int s = adj_at(adj, is64, e);
        int r = adj_at(adj, is64, (long long)NEDGES + e);
        int pos = atomicAdd(&cursor[r], 1);
        sSend[pos] = s;
        sRec[pos]  = r;
        perm[pos]  = e;
    }
}

// ---------------- Edge kernel: persistent, barrier-free K-loop ----------------
// Edges arrive sorted by destination -> per-32-row tile segmented reduce in LDS,
// one atomicAdd per (segment, column) instead of one per (edge, column).
__global__ __launch_bounds__(512, 2) void edge_kernel(
    const float* __restrict__ x, const float* __restrict__ inv,
    const int* __restrict__ sSend, const int* __restrict__ sRec,
    const int* __restrict__ perm,
    const unsigned short* __restrict__ Wm1t, const float* __restrict__ bm1,
    const unsigned short* __restrict__ Wm2t, const float* __restrict__ bm2,
    const float* __restrict__ We, const float* __restrict__ be,
    float* __restrict__ aggr)
{
    __shared__ unsigned short s_w1[128 * W1STRIDE];      // 75,776 B
    __shared__ unsigned short s_h[8 * 32 * HSTRIDE];     // 67,584 B (wave-private slices)
    __shared__ int s_recb[8 * 32];                       // 1,024 B (wave-private rec rows)

    const int t    = threadIdx.x;
    const int l    = t & 63;
    const int wid  = t >> 6;
    const int l15  = l & 15;
    const int quad = l >> 4;

    // Fill W1 LDS (once)
    for (int idx = t; idx < 128 * 36; idx += 512) {
        int n = idx / 36, c = idx % 36;
        *(uint4*)&s_w1[n * W1STRIDE + c * 8] = *(const uint4*)(Wm1t + n * K1 + c * 8);
    }

    // W2 B-fragments resident in 128 VGPRs
    short8 w2f[4][8];
    #pragma unroll
    for (int ks = 0; ks < 4; ++ks)
        #pragma unroll
        for (int nt = 0; nt < 8; ++nt)
            w2f[ks][nt] = *(const short8*)(Wm2t + (nt * 16 + l15) * HDIM + ks * 32 + quad * 8);

    // Gate weights resident in regs
    float wev[8];
    #pragma unroll
    for (int nt = 0; nt < 8; ++nt) wev[nt] = We[nt * 16 + l15];
    const float be0 = be[0];

    __syncthreads();   // the only barrier

    unsigned short* hbuf = s_h + wid * (32 * HSTRIDE);
    int* srec = s_recb + wid * 32;
    const int gwave  = blockIdx.x * 8 + wid;
    const int nwaves = gridDim.x * 8;

    for (int tile = gwave; tile < NTILES_E; tile += nwaves) {
        const int e0 = tile * 32;
        int re[2];
        unsigned offS[2], offR[2], offI[2];
        #pragma unroll
        for (int m = 0; m < 2; ++m) {
            int idx = e0 + m * 16 + l15;
            int se  = sSend[idx];
            re[m]   = sRec[idx];
            offS[m] = (unsigned)se * HDIM;
            offR[m] = (unsigned)re[m] * HDIM;
            offI[m] = (unsigned)perm[idx] * NINV;
        }

        auto aptr = [&](int s, int m) -> const float* {
            if (s < 4)  return x   + offS[m] + s * 32 + quad * 8;
            if (s < 8)  return x   + offR[m] + (s - 4) * 32 + quad * 8;
            return             inv + offI[m] + quad * 8;
        };

        // 2-deep prefetch pipeline for A fragments
        float4 F0[2][2], F1[2][2];
        #pragma unroll
        for (int m = 0; m < 2; ++m) {
            const float* p = aptr(0, m); F0[m][0] = ((const float4*)p)[0]; F0[m][1] = ((const float4*)p)[1];
            const float* q = aptr(1, m); F1[m][0] = ((const float4*)q)[0]; F1[m][1] = ((const float4*)q)[1];
        }

        floatx4 acc[2][8];
        #pragma unroll
        for (int nt = 0; nt < 8; ++nt) {
            float bv = bm1[nt * 16 + l15];
            acc[0][nt] = (floatx4){bv, bv, bv, bv};
            acc[1][nt] = acc[0][nt];
        }

        // ---- Layer 1: 9 K-steps, B from resident LDS, A from global via regs ----
        #pragma unroll
        for (int s = 0; s < 9; ++s) {
            short8 a[2];
            #pragma unroll
            for (int m = 0; m < 2; ++m) {
                float4 f0 = (s & 1) ? F1[m][0] : F0[m][0];
                float4 f1 = (s & 1) ? F1[m][1] : F0[m][1];
                a[m] = cvt8(f0, f1);
                if (s + 2 <= 8) {
                    const float* p = aptr(s + 2, m);
                    if (s & 1) { F1[m][0] = ((const float4*)p)[0]; F1[m][1] = ((const float4*)p)[1]; }
                    else       { F0[m][0] = ((const float4*)p)[0]; F0[m][1] = ((const float4*)p)[1]; }
                }
            }
            const unsigned short* wbase = s_w1 + l15 * W1STRIDE + s * 32 + quad * 8;
            #pragma unroll
            for (int nt = 0; nt < 8; ++nt) {
                short8 b = *(const short8*)(wbase + nt * 16 * W1STRIDE);
                acc[0][nt] = __builtin_amdgcn_mfma_f32_16x16x32_bf16(a[0], b, acc[0][nt], 0, 0, 0);
                acc[1][nt] = __builtin_amdgcn_mfma_f32_16x16x32_bf16(a[1], b, acc[1][nt], 0, 0, 0);
            }
        }

        // ---- L1 epilogue: SiLU -> bf16 h into wave-private LDS (no barrier) ----
        #pragma unroll
        for (int m = 0; m < 2; ++m)
            #pragma unroll
            for (int nt = 0; nt < 8; ++nt)
                #pragma unroll
                for (int r = 0; r < 4; ++r) {
                    float hv = silu_f(acc[m][nt][r]);
                    hbuf[(m * 16 + quad * 4 + r) * HSTRIDE + nt * 16 + l15] =
                        (unsigned short)(__float_as_uint(hv) >> 16);
                }

        #pragma unroll
        for (int nt = 0; nt < 8; ++nt) {
            float bv = bm2[nt * 16 + l15];
            acc[0][nt] = (floatx4){bv, bv, bv, bv};
            acc[1][nt] = acc[0][nt];
        }

        // ---- Layer 2: 4 K-steps, B from registers, A from wave-private LDS ----
        #pragma unroll
        for (int ks = 0; ks < 4; ++ks) {
            short8 a2[2];
            #pragma unroll
            for (int m = 0; m < 2; ++m) {
                int base = (m * 16 + l15) * HSTRIDE + ks * 32 + quad * 8;
                V4S8 v;
                v.d[0] = *(const int2*)(hbuf + base);
                v.d[1] = *(const int2*)(hbuf + base + 4);
                a2[m] = v.s;
            }
            #pragma unroll
            for (int nt = 0; nt < 8; ++nt) {
                acc[0][nt] = __builtin_amdgcn_mfma_f32_16x16x32_bf16(a2[0], w2f[ks][nt], acc[0][nt], 0, 0, 0);
                acc[1][nt] = __builtin_amdgcn_mfma_f32_16x16x32_bf16(a2[1], w2f[ks][nt], acc[1][nt], 0, 0, 0);
            }
        }

        // ---- Epilogue: SiLU, gate, segmented reduce over sorted rows ----
        #pragma unroll
        for (int m = 0; m < 2; ++m)
            #pragma unroll
            for (int nt = 0; nt < 8; ++nt)
                #pragma unroll
                for (int r = 0; r < 4; ++r)
                    acc[m][nt][r] = silu_f(acc[m][nt][r]);

        float g[2][4];
        #pragma unroll
        for (int m = 0; m < 2; ++m)
            #pragma unroll
            for (int r = 0; r < 4; ++r) {
                float part = 0.f;
                #pragma unroll
                for (int nt = 0; nt < 8; ++nt)
                    part = fmaf(acc[m][nt][r], wev[nt], part);
                part += __shfl_xor(part, 1);
                part += __shfl_xor(part, 2);
                part += __shfl_xor(part, 4);
                part += __shfl_xor(part, 8);
                g[m][r] = 1.0f / (1.0f + __expf(-(part + be0)));
            }

        // publish this tile's 32 rec values (wave-private, no barrier)
        if (quad == 0) { srec[l15] = re[0]; srec[16 + l15] = re[1]; }

        // two 64-column passes through the (now dead) h-buffer as f32
        float* fred = (float*)hbuf;
        #pragma unroll
        for (int half = 0; half < 2; ++half) {
            #pragma unroll
            for (int m = 0; m < 2; ++m)
                #pragma unroll
                for (int nt2 = 0; nt2 < 4; ++nt2)
                    #pragma unroll
                    for (int r = 0; r < 4; ++r)
                        fred[(m * 16 + quad * 4 + r) * FSTRIDE + nt2 * 16 + l15] =
                            acc[m][half * 4 + nt2][r] * g[m][r];

            // lane l owns column half*64 + l; rows are sorted by rec ->
            // the boundary test is wave-uniform (srec[row] broadcast)
            float* dstbase = aggr + half * 64 + l;
            float sum = 0.f;
            int prev = srec[0];
            #pragma unroll
            for (int row = 0; row < 32; ++row) {
                float v = fred[row * FSTRIDE + l];
                int rc = srec[row];
                if (rc != prev) {
                    atomicAdd(dstbase + (unsigned)prev * HDIM, sum);
                    sum = 0.f;
                    prev = rc;
                }
                sum += v;
            }
            atomicAdd(dstbase + (unsigned)prev * HDIM, sum);
        }
    }
}

// ---------------- Node kernel: same structure, no gather/gate/atomics ----------------
__global__ __launch_bounds__(256) void node_kernel(
    const float* __restrict__ x, const float* __restrict__ aggr,
    const unsigned short* __restrict__ Wu1t, const float* __restrict__ bu1,
    const unsigned short* __restrict__ Wu2t, const float* __restrict__ bu2,
    float* __restrict__ out)
{
    __shared__ unsigned short s_u1[128 * U1STRIDE];      // 67,584 B
    __shared__ unsigned short s_h[4 * 32 * HSTRIDE];     // 33,792 B

    const int t    = threadIdx.x;
    const int l    = t & 63;
    const int wid  = t >> 6;
    const int l15  = l & 15;
    const int quad = l >> 4;

    for (int idx = t; idx < 128 * 32; idx += 256) {
        int n = idx / 32, c = idx % 32;
        *(uint4*)&s_u1[n * U1STRIDE + c * 8] = *(const uint4*)(Wu1t + n * 256 + c * 8);
    }

    short8 w2f[4][8];
    #pragma unroll
    for (int ks = 0; ks < 4; ++ks)
        #pragma unroll
        for (int nt = 0; nt < 8; ++nt)
            w2f[ks][nt] = *(const short8*)(Wu2t + (nt * 16 + l15) * HDIM + ks * 32 + quad * 8);

    __syncthreads();

    unsigned short* hbuf = s_h + wid * (32 * HSTRIDE);
    const int tile = blockIdx.x * 4 + wid;
    if (tile >= NTILES_N) return;
    const int n0 = tile * 32;

    unsigned offX[2];
    #pragma unroll
    for (int m = 0; m < 2; ++m) {
        int row = n0 + m * 16 + l15;
        if (row >= NNODES) row = NNODES - 1;
        offX[m] = (unsigned)row * HDIM;
    }

    floatx4 acc[2][8];
    #pragma unroll
    for (int nt = 0; nt < 8; ++nt) {
        float bv = bu1[nt * 16 + l15];
        acc[0][nt] = (floatx4){bv, bv, bv, bv};
        acc[1][nt] = acc[0][nt];
    }

    // Layer 1: K=256 ([x | aggr]), 8 K-steps
    #pragma unroll
    for (int s = 0; s < 8; ++s) {
        short8 a[2];
        #pragma unroll
        for (int m = 0; m < 2; ++m) {
            const float* p = (s < 4) ? (x + offX[m] + s * 32 + quad * 8)
                                     : (aggr + offX[m] + (s - 4) * 32 + quad * 8);
            float4 f0 = ((const float4*)p)[0];
            float4 f1 = ((const float4*)p)[1];
            a[m] = cvt8(f0, f1);
        }
        const unsigned short* wbase = s_u1 + l15 * U1STRIDE + s * 32 + quad * 8;
        #pragma unroll
        for (int nt = 0; nt < 8; ++nt) {
            short8 b = *(const short8*)(wbase + nt * 16 * U1STRIDE);
            acc[0][nt] = __builtin_amdgcn_mfma_f32_16x16x32_bf16(a[0], b, acc[0][nt], 0, 0, 0);
            acc[1][nt] = __builtin_amdgcn_mfma_f32_16x16x32_bf16(a[1], b, acc[1][nt], 0, 0, 0);
        }
    }

    #pragma unroll
    for (int m = 0; m < 2; ++m)
        #pragma unroll
        for (int nt = 0; nt < 8; ++nt)
            #pragma unroll
            for (int r = 0; r < 4; ++r) {
                float hv = silu_f(acc[m][nt][r]);
                hbuf[(m * 16 + quad * 4 + r) * HSTRIDE + nt * 16 + l15] =
                    (unsigned short)(__float_as_uint(hv) >> 16);
            }

    #pragma unroll
    for (int nt = 0; nt < 8; ++nt) {
        float bv = bu2[nt * 16 + l15];
        acc[0][nt] = (floatx4){bv, bv, bv, bv};
        acc[1][nt] = acc[0][nt];
    }

    #pragma unroll
    for (int ks = 0; ks < 4; ++ks) {
        short8 a2[2];
        #pragma unroll
        for (int m = 0; m < 2; ++m) {
            int base = (m * 16 + l15) * HSTRIDE + ks * 32 + quad * 8;
            V4S8 v;
            v.d[0] = *(const int2*)(hbuf + base);
            v.d[1] = *(const int2*)(hbuf + base + 4);
            a2[m] = v.s;
        }
        #pragma unroll
        for (int nt = 0; nt < 8; ++nt) {
            acc[0][nt] = __builtin_amdgcn_mfma_f32_16x16x32_bf16(a2[0], w2f[ks][nt], acc[0][nt], 0, 0, 0);
            acc[1][nt] = __builtin_amdgcn_mfma_f32_16x16x32_bf16(a2[1], w2f[ks][nt], acc[1][nt], 0, 0, 0);
        }
    }

    // Residual + store (no activation after layer 2)
    #pragma unroll
    for (int m = 0; m < 2; ++m)
        #pragma unroll
        for (int r = 0; r < 4; ++r) {
            int row = n0 + m * 16 + quad * 4 + r;
            if (row < NNODES) {
                #pragma unroll
                for (int nt = 0; nt < 8; ++nt) {
                    int col = nt * 16 + l15;
                    out[(long long)row * HDIM + col] = x[(long long)row * HDIM + col] + acc[m][nt][r];
                }
            }
        }
}

extern "C" void kernel_launch(void* const* d_in, const int* in_sizes, int n_in,
                              void* d_out, int out_size, void* d_ws, size_t ws_size,
                              hipStream_t stream)
{
    const float* x   = (const float*)d_in[0];
    const void*  adj = d_in[1];
    const float* inv = (const float*)d_in[2];
    const float* Wm1 = (const float*)d_in[3];
    const float* bm1 = (const float*)d_in[4];
    const float* Wm2 = (const float*)d_in[5];
    const float* bm2 = (const float*)d_in[6];
    const float* We  = (const float*)d_in[7];
    const float* be  = (const float*)d_in[8];
    const float* Wu1 = (const float*)d_in[9];
    const float* bu1 = (const float*)d_in[10];
    const float* Wu2 = (const float*)d_in[11];
    const float* bu2 = (const float*)d_in[12];
    float* out = (float*)d_out;

    char* ws = (char*)d_ws;
    float* aggr = (float*)ws;
    size_t off = (size_t)NNODES * HDIM * 4;
    int* flag = (int*)(ws + off);            off += 16;
    unsigned short* Wm1t = (unsigned short*)(ws + off);  off += 128 * K1 * 2;
    unsigned short* Wm2t = (unsigned short*)(ws + off);  off += 128 * HDIM * 2;
    unsigned short* Wu1t = (unsigned short*)(ws + off);  off += 128 * 256 * 2;
    unsigned short* Wu2t = (unsigned short*)(ws + off);  off += 128 * HDIM * 2;
    int* hist   = (int*)(ws + off);          off += (size_t)NNODES * 4;
    int* cursor = (int*)(ws + off);          off += (size_t)NNODES * 4;
    int* sSend  = (int*)(ws + off);          off += (size_t)NEDGES * 4;
    int* sRec   = (int*)(ws + off);          off += (size_t)NEDGES * 4;
    int* perm   = (int*)(ws + off);          off += (size_t)NEDGES * 4;

    hipMemsetAsync(aggr, 0, (size_t)NNODES * HDIM * sizeof(float), stream);
    hipMemsetAsync(hist, 0, (size_t)NNODES * sizeof(int), stream);
    detect_idx64<<<1, 256, 0, stream>>>((const int*)adj, flag);
    prep_weights<<<400, 256, 0, stream>>>(Wm1, Wm2, Wu1, Wu2, Wm1t, Wm2t, Wu1t, Wu2t);
    hist_kernel<<<(NEDGES + 255) / 256, 256, 0, stream>>>(adj, flag, hist);
    scan_kernel<<<1, 1024, 0, stream>>>(hist, cursor);
    scatter_kernel<<<(NEDGES + 255) / 256, 256, 0, stream>>>(adj, flag, cursor,
                                                             sSend, sRec, perm);
    edge_kernel<<<256, 512, 0, stream>>>(x, inv, sSend, sRec, perm,
                                         Wm1t, bm1, Wm2t, bm2, We, be, aggr);
    node_kernel<<<(NTILES_N + 3) / 4, 256, 0, stream>>>(x, aggr,
                                                        Wu1t, bu1, Wu2t, bu2, out);
}